// Round 1
// baseline (453.699 us; speedup 1.0000x reference)
//
#include <hip/hip_runtime.h>
#include <math.h>

#define M_ROWS 262144
#define NCOL 64
#define GRAM_BLOCKS 256
#define GRAM_ROWS (M_ROWS / GRAM_BLOCKS)   // 1024
#define APPLY_BLOCKS 1024
#define APPLY_ROWS (M_ROWS / APPLY_BLOCKS) // 256

__device__ __forceinline__ void cmac_conj(float2& acc, const float2 a, const float2 b) {
    // acc += conj(a) * b
    acc.x = fmaf(a.x, b.x, acc.x);
    acc.x = fmaf(a.y, b.y, acc.x);
    acc.y = fmaf(a.x, b.y, acc.y);
    acc.y = fmaf(-a.y, b.x, acc.y);
}
__device__ __forceinline__ void cmac(float2& acc, const float2 a, const float2 b) {
    // acc += a * b
    acc.x = fmaf(a.x, b.x, acc.x);
    acc.x = fmaf(-a.y, b.y, acc.x);
    acc.y = fmaf(a.x, b.y, acc.y);
    acc.y = fmaf(a.y, b.x, acc.y);
}

// ---------------- G = X^H X  (64x64 complex, atomically accumulated) ----------------
__global__ __launch_bounds__(256) void gram_kernel(const float4* __restrict__ X4, float* __restrict__ G) {
    __shared__ float2 tile[64][66];  // pad 66 keeps rows 16B-aligned for b128 row reads
    const int t = threadIdx.x;
    const int j0 = (t >> 4) << 2;    // 16 j-groups of 4
    const int k0 = (t & 15) << 2;    // 16 k-groups of 4
    float2 acc[4][4];
#pragma unroll
    for (int a = 0; a < 4; ++a)
#pragma unroll
        for (int b = 0; b < 4; ++b) acc[a][b] = make_float2(0.f, 0.f);

    const int rbeg = blockIdx.x * GRAM_ROWS;
    for (int t0 = 0; t0 < GRAM_ROWS; t0 += 64) {
        const float4* src = X4 + (size_t)(rbeg + t0) * (NCOL / 2);
#pragma unroll
        for (int i = 0; i < 8; ++i) {
            const int f = t + 256 * i;     // 2048 float4 = 64 rows x 32 float4
            const int row = f >> 5;
            const int c4 = f & 31;
            *reinterpret_cast<float4*>(&tile[row][c4 * 2]) = src[f];
        }
        __syncthreads();
#pragma unroll 2
        for (int r = 0; r < 64; ++r) {
            const float4 a01 = *reinterpret_cast<const float4*>(&tile[r][j0]);
            const float4 a23 = *reinterpret_cast<const float4*>(&tile[r][j0 + 2]);
            const float4 b01 = *reinterpret_cast<const float4*>(&tile[r][k0]);
            const float4 b23 = *reinterpret_cast<const float4*>(&tile[r][k0 + 2]);
            const float2 xa[4] = {{a01.x,a01.y},{a01.z,a01.w},{a23.x,a23.y},{a23.z,a23.w}};
            const float2 xb[4] = {{b01.x,b01.y},{b01.z,b01.w},{b23.x,b23.y},{b23.z,b23.w}};
#pragma unroll
            for (int a = 0; a < 4; ++a)
#pragma unroll
                for (int b = 0; b < 4; ++b) cmac_conj(acc[a][b], xa[a], xb[b]);
        }
        __syncthreads();
    }
#pragma unroll
    for (int a = 0; a < 4; ++a)
#pragma unroll
        for (int b = 0; b < 4; ++b) {
            const int idx = (j0 + a) * NCOL + (k0 + b);
            atomicAdd(&G[2 * idx], acc[a][b].x);
            atomicAdd(&G[2 * idx + 1], acc[a][b].y);
        }
}

// ---------------- Cholesky (upper R) of G, then in-place R^{-1} ----------------
__global__ __launch_bounds__(256) void cholinv_kernel(const float2* __restrict__ G, float2* __restrict__ RinvOut) {
    __shared__ float2 A[64][64];
    __shared__ float2 rowbuf[64];
    __shared__ float dinv[64];
    const int t = threadIdx.x;
    for (int i = t; i < 4096; i += 256) A[i >> 6][i & 63] = G[i];
    __syncthreads();

    // right-looking complex Cholesky, upper triangular R in-place
    for (int i = 0; i < 64; ++i) {
        if (t == 0) {
            const float d = sqrtf(fmaxf(A[i][i].x, 1e-30f));
            dinv[i] = 1.0f / d;
            A[i][i] = make_float2(d, 0.f);
        }
        __syncthreads();
        const float di = dinv[i];
        for (int k = i + 1 + t; k < 64; k += 256) {
            A[i][k].x *= di;
            A[i][k].y *= di;
        }
        __syncthreads();
        const int n = 63 - i;
        for (int idx = t; idx < n * n; idx += 256) {
            const int j = i + 1 + idx / n;
            const int k = i + 1 + idx % n;
            if (k >= j) {
                const float2 rij = A[i][j];  // R[i][j]
                const float2 rik = A[i][k];  // R[i][k]
                float2 v = A[j][k];
                // A[j][k] -= conj(rij) * rik
                v.x -= rij.x * rik.x + rij.y * rik.y;
                v.y -= rij.x * rik.y - rij.y * rik.x;
                A[j][k] = v;
            }
        }
        __syncthreads();
    }

    // in-place upper-triangular inversion: upper(A) := R^{-1}
    if (t < 64) A[t][t] = make_float2(dinv[t], 0.f);
    __syncthreads();
    for (int i = 62; i >= 0; --i) {
        if (t < 64 && t > i) rowbuf[t] = A[i][t];   // save R row i before overwrite
        __syncthreads();
        if (t < 64 && t > i) {
            const int k = t;
            float2 s = make_float2(0.f, 0.f);
            for (int j = i + 1; j <= k; ++j) cmac(s, rowbuf[j], A[j][k]); // A[j][k] = V[j][k]
            A[i][k] = make_float2(-s.x * dinv[i], -s.y * dinv[i]);
        }
        __syncthreads();
    }
    for (int i = t; i < 4096; i += 256) {
        const int r = i >> 6, c = i & 63;
        RinvOut[i] = (c >= r) ? A[r][c] : make_float2(0.f, 0.f);
    }
}

// ---------------- Q = X * Rinv ----------------
__global__ __launch_bounds__(256) void apply_kernel(const float4* __restrict__ X4,
                                                    const float4* __restrict__ Rinv4,
                                                    float4* __restrict__ Q4) {
    __shared__ float2 tile[64][64];  // XOR-swizzled in col index: element j at col (j ^ ((row&7)<<1))
    __shared__ float2 W[64][64];     // Rinv, row-major
    const int t = threadIdx.x;
#pragma unroll
    for (int i = 0; i < 8; ++i) {
        const int f = t + 256 * i;   // 2048 float4
        reinterpret_cast<float4*>(&W[0][0])[f] = Rinv4[f];
    }
    const int r0 = (t >> 4) << 2;
    const int k0 = (t & 15) << 2;
    const int rbeg = blockIdx.x * APPLY_ROWS;
    for (int t0 = 0; t0 < APPLY_ROWS; t0 += 64) {
        const float4* src = X4 + (size_t)(rbeg + t0) * (NCOL / 2);
#pragma unroll
        for (int i = 0; i < 8; ++i) {
            const int f = t + 256 * i;
            const int row = f >> 5;
            const int c4 = f & 31;
            const int col2 = (c4 * 2) ^ ((row & 7) << 1);  // even swizzle keeps float4 pairs adjacent+aligned
            *reinterpret_cast<float4*>(&tile[row][col2]) = src[f];
        }
        __syncthreads();
        float2 acc[4][4];
#pragma unroll
        for (int a = 0; a < 4; ++a)
#pragma unroll
            for (int b = 0; b < 4; ++b) acc[a][b] = make_float2(0.f, 0.f);
#pragma unroll 2
        for (int j = 0; j < 64; ++j) {
            float2 xr[4];
#pragma unroll
            for (int a = 0; a < 4; ++a) {
                const int r = r0 + a;
                xr[a] = tile[r][j ^ ((r & 7) << 1)];
            }
            const float4 w01 = *reinterpret_cast<const float4*>(&W[j][k0]);
            const float4 w23 = *reinterpret_cast<const float4*>(&W[j][k0 + 2]);
            const float2 wb[4] = {{w01.x,w01.y},{w01.z,w01.w},{w23.x,w23.y},{w23.z,w23.w}};
#pragma unroll
            for (int a = 0; a < 4; ++a)
#pragma unroll
                for (int b = 0; b < 4; ++b) cmac(acc[a][b], xr[a], wb[b]);
        }
#pragma unroll
        for (int a = 0; a < 4; ++a) {
            const size_t row = (size_t)(rbeg + t0 + r0 + a);
            const float4 o01 = make_float4(acc[a][0].x, acc[a][0].y, acc[a][1].x, acc[a][1].y);
            const float4 o23 = make_float4(acc[a][2].x, acc[a][2].y, acc[a][3].x, acc[a][3].y);
            Q4[row * (NCOL / 2) + (k0 >> 1)] = o01;
            Q4[row * (NCOL / 2) + (k0 >> 1) + 1] = o23;
        }
        __syncthreads();
    }
}

extern "C" void kernel_launch(void* const* d_in, const int* in_sizes, int n_in,
                              void* d_out, int out_size, void* d_ws, size_t ws_size,
                              hipStream_t stream) {
    (void)in_sizes; (void)n_in; (void)out_size; (void)ws_size;
    const float4* X4 = reinterpret_cast<const float4*>(d_in[0]);
    float* G = reinterpret_cast<float*>(d_ws);                       // 8192 floats (32 KB)
    float2* Rinv = reinterpret_cast<float2*>(G + 2 * NCOL * NCOL);   // 4096 float2 (32 KB)
    float4* Q4 = reinterpret_cast<float4*>(d_out);

    hipMemsetAsync(G, 0, 2 * NCOL * NCOL * sizeof(float), stream);
    gram_kernel<<<GRAM_BLOCKS, 256, 0, stream>>>(X4, G);
    cholinv_kernel<<<1, 256, 0, stream>>>(reinterpret_cast<const float2*>(G), Rinv);
    apply_kernel<<<APPLY_BLOCKS, 256, 0, stream>>>(X4, reinterpret_cast<const float4*>(Rinv), Q4);
}